// Round 3
// baseline (408.451 us; speedup 1.0000x reference)
//
#include <hip/hip_runtime.h>

// GCN: B=256 blocks, N=512 nodes, D_IN=D_HID=256, D_OUT=128, 3 steps.
// Round-3 schedule (no standalone conversion passes):
//   k_wconv : W0,W1 -> bf16 transposed (tiny)
//   k_lin0  : Z0 = bf16(feat) @ W0 — reg-stages fp32 feat, computes nz in-staging
//   k_propf : X = relu(diag(1/rowsum) * (adj_raw @ Z)) — reg-stages fp32 adj,
//             rowsum computed BY MFMA (B-frag = nz broadcast columns)
//   k_linear: Z1 = X1 @ W1 (bf16 fast path, global_load_lds)
//   k_propf : X2
//   k_tail  : out = relu((a0/rowsum0 @ X2) @ W2) @ Wout   (associativity)

typedef __attribute__((ext_vector_type(8))) short short8;
typedef __attribute__((ext_vector_type(4))) float f32x4;

__device__ __forceinline__ unsigned short f2bf(float x) {
  unsigned u = __float_as_uint(x);
  unsigned r = u + 0x7fffu + ((u >> 16) & 1u);
  return (unsigned short)(r >> 16);
}
__device__ __forceinline__ float bf2f(unsigned short b) {
  return __uint_as_float(((unsigned)b) << 16);
}
// packed fp32 pair -> bf16x2 (RNE), single HW op
__device__ __forceinline__ unsigned pkbf(float lo, float hi) {
  unsigned r;
  asm("v_cvt_pk_bf16_f32 %0, %1, %2" : "=v"(r) : "v"(lo), "v"(hi));
  return r;
}

#define GLDS(g, l) __builtin_amdgcn_global_load_lds( \
    (const __attribute__((address_space(1))) void*)(g), \
    (__attribute__((address_space(3))) void*)(l), 16, 0, 0)

// XCD-chunked bijective swizzle for grid 2048 (cpx = 256, 8 XCDs)
__device__ __forceinline__ int swz2048(int bid) {
  return (bid & 7) * 256 + (bid >> 3);
}

// ---------------------------------------------------------------------------
// W0/W1 (256,256) fp32 -> Wt bf16 TRANSPOSED: Wt[s][n][k] = W_s[k][n]
__global__ void k_wconv(const float* __restrict__ W0, const float* __restrict__ W1,
                        unsigned short* __restrict__ Wt) {
  int s = blockIdx.x >> 8;
  int n = blockIdx.x & 255;
  int k = threadIdx.x;
  const float* W = s ? W1 : W0;
  Wt[(size_t)s * 65536 + n * 256 + k] = f2bf(W[(size_t)k * 256 + n]);
}

// ---------------------------------------------------------------------------
// bf16 fast-path MFMA mainloop (128x128 tile, BK=64, 4 waves as 2x2 of 64x64)
// A,B bf16 row-major [rows][K]; LDS XOR swizzle byte ^= ((row&7)<<4).
__device__ __forceinline__ void gemm_tile(
    const char* Ag, int ldaB, const char* Bg, int ldbB, int nkt,
    char* ldsA, char* ldsB, f32x4 acc[4][4], int wm, int wn, int lane, int tid) {
  for (int kt = 0; kt < nkt; ++kt) {
#pragma unroll
    for (int q = 0; q < 4; ++q) {
      int P = (q * 256 + tid) * 16;          // physical LDS byte (linear)
      int L = P ^ (((P >> 7) & 7) << 4);     // logical byte (involution)
      int row = L >> 7, cb = L & 127;
      GLDS(Ag + (size_t)row * ldaB + kt * 128 + cb, ldsA + P);
      GLDS(Bg + (size_t)row * ldbB + kt * 128 + cb, ldsB + P);
    }
    __syncthreads();
#pragma unroll
    for (int ks = 0; ks < 2; ++ks) {
      short8 af[4], bfr[4];
      int c = ks * 64 + ((lane >> 4) << 4);
#pragma unroll
      for (int m = 0; m < 4; ++m) {
        int row = wm * 64 + m * 16 + (lane & 15);
        af[m] = *(const short8*)(ldsA + ((row * 128 + c) ^ ((row & 7) << 4)));
      }
#pragma unroll
      for (int n = 0; n < 4; ++n) {
        int row = wn * 64 + n * 16 + (lane & 15);
        bfr[n] = *(const short8*)(ldsB + ((row * 128 + c) ^ ((row & 7) << 4)));
      }
#pragma unroll
      for (int m = 0; m < 4; ++m)
#pragma unroll
        for (int n = 0; n < 4; ++n)
          acc[m][n] = __builtin_amdgcn_mfma_f32_16x16x32_bf16(af[m], bfr[n], acc[m][n], 0, 0, 0);
    }
    __syncthreads();
  }
}

// ---------------------------------------------------------------------------
// Z0 = bf16(feat) @ W0, Zt transposed out; nz computed in-staging.
// M=131072, N=256, K=256. grid = 2048. A reg-staged from fp32.
__global__ __launch_bounds__(256) void k_lin0(const float* __restrict__ feat,
                                              const unsigned short* __restrict__ Wt,
                                              unsigned short* __restrict__ Zt,
                                              float* __restrict__ nzOut) {
  __shared__ char ldsA[16384];
  __shared__ char ldsB[16384];
  int tid = threadIdx.x, lane = tid & 63, wid = tid >> 6;
  int wm = wid >> 1, wn = wid & 1;
  int tile = swz2048(blockIdx.x);
  int tm = tile >> 1, tn = tile & 1;
  const float* Ag = feat + (size_t)tm * 128 * 256;
  const char* Bg = (const char*)(Wt + (size_t)tn * 128 * 256);
  int r = tid >> 1, hk = tid & 1;
  const float* myrow = Ag + (size_t)r * 256 + hk * 32;
  float ssq = 0.f;
  f32x4 acc[4][4];
#pragma unroll
  for (int m = 0; m < 4; ++m)
#pragma unroll
    for (int n = 0; n < 4; ++n) { f32x4 z = {0.f, 0.f, 0.f, 0.f}; acc[m][n] = z; }

  for (int kt = 0; kt < 4; ++kt) {
#pragma unroll
    for (int q = 0; q < 4; ++q) {
      int P = (q * 256 + tid) * 16;
      int L = P ^ (((P >> 7) & 7) << 4);
      int row = L >> 7, cb = L & 127;
      GLDS(Bg + (size_t)row * 512 + kt * 128 + cb, ldsB + P);
    }
    float4 f[8];
#pragma unroll
    for (int q = 0; q < 8; ++q) f[q] = ((const float4*)(myrow + kt * 64))[q];
#pragma unroll
    for (int q = 0; q < 8; ++q)
      ssq += f[q].x * f[q].x + f[q].y * f[q].y + f[q].z * f[q].z + f[q].w * f[q].w;
#pragma unroll
    for (int q = 0; q < 4; ++q) {
      uint4 w;
      w.x = pkbf(f[2 * q].x, f[2 * q].y);
      w.y = pkbf(f[2 * q].z, f[2 * q].w);
      w.z = pkbf(f[2 * q + 1].x, f[2 * q + 1].y);
      w.w = pkbf(f[2 * q + 1].z, f[2 * q + 1].w);
      int cb = hk * 64 + q * 16;
      *(uint4*)(ldsA + ((r * 128 + cb) ^ ((r & 7) << 4))) = w;
    }
    __syncthreads();
#pragma unroll
    for (int ks = 0; ks < 2; ++ks) {
      short8 af[4], bfr[4];
      int c = ks * 64 + ((lane >> 4) << 4);
#pragma unroll
      for (int m = 0; m < 4; ++m) {
        int row = wm * 64 + m * 16 + (lane & 15);
        af[m] = *(const short8*)(ldsA + ((row * 128 + c) ^ ((row & 7) << 4)));
      }
#pragma unroll
      for (int n = 0; n < 4; ++n) {
        int row = wn * 64 + n * 16 + (lane & 15);
        bfr[n] = *(const short8*)(ldsB + ((row * 128 + c) ^ ((row & 7) << 4)));
      }
#pragma unroll
      for (int m = 0; m < 4; ++m)
#pragma unroll
        for (int n = 0; n < 4; ++n)
          acc[m][n] = __builtin_amdgcn_mfma_f32_16x16x32_bf16(af[m], bfr[n], acc[m][n], 0, 0, 0);
    }
    __syncthreads();
  }

  float tot = ssq + __shfl_xor(ssq, 1);
  if (hk == 0 && tn == 0) nzOut[(size_t)tm * 128 + r] = (tot > 0.f) ? 1.f : 0.f;

  int b = tm >> 2;
  int node_base = ((tm & 3) * 128) + wm * 64;
  int h_base = tn * 128 + wn * 64;
#pragma unroll
  for (int m = 0; m < 4; ++m) {
    int node = node_base + m * 16 + ((lane >> 4) << 2);
#pragma unroll
    for (int n = 0; n < 4; ++n) {
      int h = h_base + n * 16 + (lane & 15);
      f32x4 v = acc[m][n];
      ushort4 p;
      p.x = f2bf(v[0]); p.y = f2bf(v[1]); p.z = f2bf(v[2]); p.w = f2bf(v[3]);
      *(ushort4*)(Zt + ((size_t)b * 256 + h) * 512 + node) = p;
    }
  }
}

// ---------------------------------------------------------------------------
// X = relu(diag(1/rowsum) * (adj_raw @ Z))  per block: M=512, N=256, K=512.
// A reg-staged from raw fp32; rowsum = A@nz computed by MFMA (broadcast B-frag).
// grid = 2048.
__global__ __launch_bounds__(256) void k_propf(const float* __restrict__ adj,
                                               const unsigned short* __restrict__ Zt,
                                               const float* __restrict__ nz,
                                               unsigned short* __restrict__ Xout) {
  __shared__ char ldsA[16384];
  __shared__ char ldsB[16384];
  __shared__ char nzbfL[1024];
  int tid = threadIdx.x, lane = tid & 63, wid = tid >> 6;
  int wm = wid >> 1, wn = wid & 1;
  int tile = swz2048(blockIdx.x);
  int b = tile >> 3, tm = (tile >> 1) & 3, tn = tile & 1;
  const float* Ag = adj + ((size_t)b * 512 + tm * 128) * 512;
  const char* Bg = (const char*)(Zt + ((size_t)b * 256 + tn * 128) * 512);
  // nz -> bf16 broadcast table in LDS
  {
    float2 nv = ((const float2*)(nz + (size_t)b * 512))[tid];
    ((unsigned*)nzbfL)[tid] = pkbf(nv.x, nv.y);
  }
  int r = tid >> 1, hk = tid & 1;
  const float* myrow = Ag + (size_t)r * 512 + hk * 32;
  f32x4 acc[4][4];
  f32x4 acc_rs[4];
#pragma unroll
  for (int m = 0; m < 4; ++m) {
    f32x4 z = {0.f, 0.f, 0.f, 0.f};
    acc_rs[m] = z;
#pragma unroll
    for (int n = 0; n < 4; ++n) acc[m][n] = z;
  }

  for (int kt = 0; kt < 8; ++kt) {
#pragma unroll
    for (int q = 0; q < 4; ++q) {
      int P = (q * 256 + tid) * 16;
      int L = P ^ (((P >> 7) & 7) << 4);
      int row = L >> 7, cb = L & 127;
      GLDS(Bg + (size_t)row * 1024 + kt * 128 + cb, ldsB + P);
    }
    float4 f[8];
#pragma unroll
    for (int q = 0; q < 8; ++q) f[q] = ((const float4*)(myrow + kt * 64))[q];
#pragma unroll
    for (int q = 0; q < 4; ++q) {
      uint4 w;
      w.x = pkbf(f[2 * q].x, f[2 * q].y);
      w.y = pkbf(f[2 * q].z, f[2 * q].w);
      w.z = pkbf(f[2 * q + 1].x, f[2 * q + 1].y);
      w.w = pkbf(f[2 * q + 1].z, f[2 * q + 1].w);
      int cb = hk * 64 + q * 16;
      *(uint4*)(ldsA + ((r * 128 + cb) ^ ((r & 7) << 4))) = w;
    }
    __syncthreads();
#pragma unroll
    for (int ks = 0; ks < 2; ++ks) {
      short8 af[4], bfr[4], nzf;
      int c = ks * 64 + ((lane >> 4) << 4);
      nzf = *(const short8*)(nzbfL + kt * 128 + c);
#pragma unroll
      for (int m = 0; m < 4; ++m) {
        int row = wm * 64 + m * 16 + (lane & 15);
        af[m] = *(const short8*)(ldsA + ((row * 128 + c) ^ ((row & 7) << 4)));
      }
#pragma unroll
      for (int n = 0; n < 4; ++n) {
        int row = wn * 64 + n * 16 + (lane & 15);
        bfr[n] = *(const short8*)(ldsB + ((row * 128 + c) ^ ((row & 7) << 4)));
      }
#pragma unroll
      for (int m = 0; m < 4; ++m)
        acc_rs[m] = __builtin_amdgcn_mfma_f32_16x16x32_bf16(af[m], nzf, acc_rs[m], 0, 0, 0);
#pragma unroll
      for (int m = 0; m < 4; ++m)
#pragma unroll
        for (int n = 0; n < 4; ++n)
          acc[m][n] = __builtin_amdgcn_mfma_f32_16x16x32_bf16(af[m], bfr[n], acc[m][n], 0, 0, 0);
    }
    __syncthreads();
  }

  int node_base = tm * 128 + wm * 64;
  int h_base = tn * 128 + wn * 64;
#pragma unroll
  for (int m = 0; m < 4; ++m) {
    int node = node_base + m * 16 + ((lane >> 4) << 2);
    float inv[4];
#pragma unroll
    for (int r2 = 0; r2 < 4; ++r2) {
      float rsv = acc_rs[m][r2];
      inv[r2] = 1.f / ((rsv == 0.f) ? 1.f : rsv);
    }
#pragma unroll
    for (int n = 0; n < 4; ++n) {
      int h = h_base + n * 16 + (lane & 15);
#pragma unroll
      for (int r2 = 0; r2 < 4; ++r2) {
        float v = acc[m][n][r2] * inv[r2];
        v = v > 0.f ? v : 0.f;
        Xout[((size_t)b * 512 + node + r2) * 256 + h] = f2bf(v);
      }
    }
  }
}

// ---------------------------------------------------------------------------
// Z = X @ W  (bf16 fast path). M=131072, N=256, K=256. grid = 2048.
__global__ __launch_bounds__(256) void k_linear(const unsigned short* __restrict__ X,
                                                const unsigned short* __restrict__ Wt,
                                                unsigned short* __restrict__ Zt) {
  __shared__ char lds[32768];
  int tid = threadIdx.x, lane = tid & 63, wid = tid >> 6;
  int wm = wid >> 1, wn = wid & 1;
  int tile = swz2048(blockIdx.x);
  int tm = tile >> 1, tn = tile & 1;
  const char* Ag = (const char*)(X + (size_t)tm * 128 * 256);
  const char* Bg = (const char*)(Wt + (size_t)tn * 128 * 256);
  f32x4 acc[4][4];
#pragma unroll
  for (int m = 0; m < 4; ++m)
#pragma unroll
    for (int n = 0; n < 4; ++n) { f32x4 z = {0.f, 0.f, 0.f, 0.f}; acc[m][n] = z; }
  gemm_tile(Ag, 512, Bg, 512, 4, lds, lds + 16384, acc, wm, wn, lane, tid);
  int b = tm >> 2;
  int node_base = ((tm & 3) * 128) + wm * 64;
  int h_base = tn * 128 + wn * 64;
#pragma unroll
  for (int m = 0; m < 4; ++m) {
    int node = node_base + m * 16 + ((lane >> 4) << 2);
#pragma unroll
    for (int n = 0; n < 4; ++n) {
      int h = h_base + n * 16 + (lane & 15);
      f32x4 v = acc[m][n];
      ushort4 p;
      p.x = f2bf(v[0]); p.y = f2bf(v[1]); p.z = f2bf(v[2]); p.w = f2bf(v[3]);
      *(ushort4*)(Zt + ((size_t)b * 256 + h) * 512 + node) = p;
    }
  }
}

// ---------------------------------------------------------------------------
// Tail (one block per batch-block b):
//   inv = 1/rowsum0 (from raw adj row 0 & nz) ; y = (a0*inv) @ X2 ;
//   x3 = relu(y @ W2) ; out = x3 @ Wout
__global__ __launch_bounds__(256) void k_tail(const float* __restrict__ adj,
                                              const unsigned short* __restrict__ X2,
                                              const float* __restrict__ nz,
                                              const float* __restrict__ W2,
                                              const float* __restrict__ Wout,
                                              float* __restrict__ out) {
  __shared__ float aL[512];
  __shared__ float red[4];
  __shared__ float sInv;
  __shared__ float yL[8][256];
  __shared__ float y[256];
  __shared__ float x3[256];
  int b = blockIdx.x, tid = threadIdx.x;
  {
    float2 av = ((const float2*)(adj + (size_t)b * 512 * 512))[tid];
    float2 nv = ((const float2*)(nz + (size_t)b * 512))[tid];
    aL[2 * tid] = av.x;
    aL[2 * tid + 1] = av.y;
    float p = av.x * nv.x + av.y * nv.y;
#pragma unroll
    for (int off = 1; off < 64; off <<= 1) p += __shfl_xor(p, off);
    if ((tid & 63) == 0) red[tid >> 6] = p;
  }
  __syncthreads();
  if (tid == 0) {
    float s = red[0] + red[1] + red[2] + red[3];
    sInv = 1.f / ((s == 0.f) ? 1.f : s);
  }
  __syncthreads();
  // phase 1: y[h] = inv * sum_j a0[j] * X2[j][h]
  {
    int hg = tid & 31, jg = tid >> 5;
    float acc8[8] = {0.f, 0.f, 0.f, 0.f, 0.f, 0.f, 0.f, 0.f};
    const unsigned short* Xb = X2 + (size_t)b * 512 * 256;
    for (int jj = 0; jj < 64; ++jj) {
      int j = jj * 8 + jg;
      short8 xv = *(const short8*)(Xb + (size_t)j * 256 + hg * 8);
      float a = aL[j];
#pragma unroll
      for (int r = 0; r < 8; ++r) acc8[r] += a * bf2f((unsigned short)xv[r]);
    }
#pragma unroll
    for (int r = 0; r < 8; ++r) yL[jg][hg * 8 + r] = acc8[r];
  }
  __syncthreads();
  {
    float s = 0.f;
#pragma unroll
    for (int g = 0; g < 8; ++g) s += yL[g][tid];
    y[tid] = s * sInv;
  }
  __syncthreads();
  // phase 2: x3[o] = relu(sum_k y[k] * W2[k][o])
  {
    float s = 0.f;
    for (int k = 0; k < 256; ++k) s += y[k] * W2[(size_t)k * 256 + tid];
    x3[tid] = s > 0.f ? s : 0.f;
  }
  __syncthreads();
  // phase 3: out[b][o] = sum_h x3[h] * Wout[h][o]
  if (tid < 128) {
    float s = 0.f;
    for (int h = 0; h < 256; ++h) s += x3[h] * Wout[(size_t)h * 128 + tid];
    out[(size_t)b * 128 + tid] = s;
  }
}

// ---------------------------------------------------------------------------
extern "C" void kernel_launch(void* const* d_in, const int* in_sizes, int n_in,
                              void* d_out, int out_size, void* d_ws, size_t ws_size,
                              hipStream_t stream) {
  (void)in_sizes; (void)n_in; (void)out_size; (void)ws_size;
  const float* feat = (const float*)d_in[0];
  const float* adj  = (const float*)d_in[1];
  const float* W0   = (const float*)d_in[2];
  const float* W1   = (const float*)d_in[3];
  const float* W2   = (const float*)d_in[4];
  const float* Wout = (const float*)d_in[5];
  float* out = (float*)d_out;

  char* ws = (char*)d_ws;
  unsigned short* Xbuf = (unsigned short*)(ws);                 //  67108864 B
  unsigned short* Zt   = (unsigned short*)(ws + 67108864);      //  67108864 B
  float* nzbuf         = (float*)(ws + 134217728);              //    524288 B
  unsigned short* Wt   = (unsigned short*)(ws + 134742016);     //    262144 B
  // total ws usage: ~135 MB

  k_wconv<<<512, 256, 0, stream>>>(W0, W1, Wt);

  // step 0: fused feat-conversion linear (also writes nz), then propagation
  k_lin0<<<2048, 256, 0, stream>>>(feat, Wt, Zt, nzbuf);
  k_propf<<<2048, 256, 0, stream>>>(adj, Zt, nzbuf, Xbuf);
  // step 1
  k_linear<<<2048, 256, 0, stream>>>(Xbuf, Wt + 65536, Zt);
  k_propf<<<2048, 256, 0, stream>>>(adj, Zt, nzbuf, Xbuf);
  // step 2 (linear folded into tail via associativity) + output projection
  k_tail<<<256, 256, 0, stream>>>(adj, Xbuf, nzbuf, W2, Wout, out);
}